// Round 4
// baseline (396.090 us; speedup 1.0000x reference)
//
#include <hip/hip_runtime.h>
#include <stdint.h>

typedef unsigned short ushort_t;
typedef __bf16 bf16x8 __attribute__((ext_vector_type(8)));
typedef float f32x4 __attribute__((ext_vector_type(4)));

#define TT   65536   // tokens (8*8192)
#define DD   256
#define FF   1024
#define EE   8
#define CAP  10240   // ceil(1.25*T/E) == 80*128 exactly

typedef __attribute__((address_space(1))) void gvoid;
typedef __attribute__((address_space(3))) void lvoid;

__device__ inline unsigned short f2bf(float f) {
  unsigned int u = __builtin_bit_cast(unsigned int, f);
  u += 0x7fffu + ((u >> 16) & 1u);   // round-to-nearest-even
  return (unsigned short)(u >> 16);
}
__device__ inline void gll16(const void* g, void* l) {
  __builtin_amdgcn_global_load_lds((gvoid*)(uintptr_t)g, (lvoid*)(uintptr_t)l, 16, 0, 0);
}

// --- gating + f32->bf16 cast of X + fused histogram: 1 wave/token ------
__global__ __launch_bounds__(256) void gate_cast_kernel(
    const float* __restrict__ X, const float* __restrict__ GW,
    const float* __restrict__ GB, int* __restrict__ eidx,
    float* __restrict__ prob, ushort_t* __restrict__ xbf,
    int* __restrict__ bh)
{
  // expert-major, lane-minor, stride 66 doubles: b64 writes at bank floor,
  // reads are 4x contiguous ds_read_b128 per thread (conflict-free).
  __shared__ __align__(16) double gl[4][8][66];
  __shared__ double lg[4][8];
  const int w = threadIdx.x >> 6, lane = threadIdx.x & 63;
  const int tok = blockIdx.x * 4 + w;
  const float4 xv = *(const float4*)(X + (size_t)tok * DD + lane * 4);
  ushort_t pk[4] = {f2bf(xv.x), f2bf(xv.y), f2bf(xv.z), f2bf(xv.w)};
  *(uint2*)(xbf + (size_t)tok * DD + lane * 4) = *(const uint2*)pk;

  float xs[4] = {xv.x, xv.y, xv.z, xv.w};
  double acc[EE];
  #pragma unroll
  for (int e = 0; e < EE; e++) acc[e] = 0.0;
  #pragma unroll
  for (int dd = 0; dd < 4; dd++) {
    double xf = (double)xs[dd];
    const float4 g0 = *(const float4*)(GW + (size_t)(lane * 4 + dd) * EE);
    const float4 g1 = *(const float4*)(GW + (size_t)(lane * 4 + dd) * EE + 4);
    acc[0] += xf * (double)g0.x; acc[1] += xf * (double)g0.y;
    acc[2] += xf * (double)g0.z; acc[3] += xf * (double)g0.w;
    acc[4] += xf * (double)g1.x; acc[5] += xf * (double)g1.y;
    acc[6] += xf * (double)g1.z; acc[7] += xf * (double)g1.w;
  }
  #pragma unroll
  for (int e = 0; e < EE; e++) gl[w][e][lane] = acc[e];
  __syncthreads();
  const int eg = lane >> 3, j = lane & 7;
  const double* row = gl[w][eg];
  double s = 0.0;
  #pragma unroll
  for (int k = 0; k < 8; k++) s += row[j * 8 + k];
  s += __shfl_xor(s, 4); s += __shfl_xor(s, 2); s += __shfl_xor(s, 1);
  if (j == 0) lg[w][eg] = s + (double)GB[eg];
  __syncthreads();
  if (lane == 0) {
    double l8[EE];
    #pragma unroll
    for (int e = 0; e < EE; e++) l8[e] = lg[w][e];
    int best = 0; double bm = l8[0];
    #pragma unroll
    for (int e = 1; e < EE; e++) if (l8[e] > bm) { bm = l8[e]; best = e; }
    float sm = 0.f;
    #pragma unroll
    for (int e = 0; e < EE; e++) sm += __expf((float)(l8[e] - bm));
    eidx[tok] = best; prob[tok] = 1.0f / sm;
    atomicAdd(&bh[(tok >> 8) * EE + best], 1);
  }
}

// ------ merged scan+rank+zero-dropped: per block local reduction ------
__global__ __launch_bounds__(256) void rankscan_kernel(
    const int* __restrict__ eidx, const int* __restrict__ bh,
    int* __restrict__ tfs, int* __restrict__ counts, float* __restrict__ Y)
{
  __shared__ int tot[256][EE + 1];   // +1 pad: break 16-way bank conflict
  __shared__ int pre[256][EE + 1];
  __shared__ int wh[4][EE];
  __shared__ int base[EE];
  const int b = blockIdx.x, tid = threadIdx.x, w = tid >> 6, lane = tid & 63;
  #pragma unroll
  for (int e = 0; e < EE; e++) {
    int v = bh[tid * EE + e];
    tot[tid][e] = v;
    pre[tid][e] = (tid < b) ? v : 0;
  }
  __syncthreads();
  for (int off = 128; off >= 1; off >>= 1) {
    if (tid < off) {
      #pragma unroll
      for (int e = 0; e < EE; e++) {
        tot[tid][e] += tot[tid + off][e];
        pre[tid][e] += pre[tid + off][e];
      }
    }
    __syncthreads();
  }
  if (tid < EE) {
    if (b == 0) counts[tid] = tot[0][tid];
    base[tid] = pre[0][tid];
  }
  __syncthreads();
  const int t = b * 256 + tid;
  const int e = eidx[t];
  const unsigned long long ltmask = (1ull << lane) - 1ull;
  int myrank = 0;
  #pragma unroll
  for (int ee = 0; ee < EE; ee++) {
    unsigned long long m = __ballot(e == ee);
    if (e == ee) myrank = __popcll(m & ltmask);
    if (lane == 0) wh[w][ee] = __popcll(m);
  }
  __syncthreads();
  int pos = base[e] + myrank;
  for (int ww = 0; ww < w; ww++) pos += wh[ww][e];
  if (pos < CAP) {
    tfs[e * CAP + pos] = t;
  } else {
    float4 z = {0.f, 0.f, 0.f, 0.f};
    float4* yp = (float4*)(Y + (size_t)t * DD);
    for (int i = 0; i < DD / 4; i++) yp[i] = z;
  }
}

// ------ both weight transposes (f32->bf16) in one dispatch ------------
// XCD-affinity swizzle: expert e's tiles run on XCD e, so w1t/w2t land in
// the same per-XCD L2 that ffn (same swizzle) will read them from.
__global__ __launch_bounds__(256) void transpose2_kernel(
    const float* __restrict__ W1, const float* __restrict__ W2,
    ushort_t* __restrict__ w1t, ushort_t* __restrict__ w2t)
{
  __shared__ __align__(16) ushort_t tile[64][72];
  int id = blockIdx.x;
  const float* src; ushort_t* dst; int R, Cc, bx, by, e;
  if (id < 512) {            // W1 [E][D][F] -> w1t [E][F][D]
    id = (id & 7) * 64 + (id >> 3);          // 512 = 8*64, bijective
    e = id >> 6; int r = id & 63; bx = r & 15; by = r >> 4;
    src = W1; dst = w1t; R = DD; Cc = FF;
  } else {                   // W2 [E][F][D] -> w2t [E][D][F]
    id -= 512;
    id = (id & 7) * 64 + (id >> 3);
    e = id >> 6; int r = id & 63; bx = r & 3; by = r >> 2;
    src = W2; dst = w2t; R = FF; Cc = DD;
  }
  const size_t ebase = (size_t)e * R * Cc;
  const int r0 = by * 64, c0 = bx * 64;
  // XOR column-slot swizzle keyed on r>>3: the read below walks rows in
  // steps of 8 (stride 8*144B == 0 mod 32 banks) -> was 8-way conflicted.
  #pragma unroll
  for (int it = 0; it < 4; it++) {
    int idx = threadIdx.x + it * 256;
    int r = idx >> 4, sl = idx & 15;
    float4 v = *(const float4*)(src + ebase + (size_t)(r0 + r) * Cc + c0 + sl * 4);
    ushort_t u[4] = {f2bf(v.x), f2bf(v.y), f2bf(v.z), f2bf(v.w)};
    *(uint2*)&tile[r][(sl ^ (r >> 3)) * 4] = *(const uint2*)u;
  }
  __syncthreads();
  #pragma unroll
  for (int it = 0; it < 2; it++) {
    int idx = threadIdx.x + it * 256;
    int cc = idx >> 3, r8 = (idx & 7) * 8;
    const int ccs = (((cc >> 2) ^ (r8 >> 3)) << 2) | (cc & 3);
    uint4 o;
    ushort_t* op = (ushort_t*)&o;
    #pragma unroll
    for (int jj = 0; jj < 8; jj++) op[jj] = tile[r8 + jj][ccs];
    *(uint4*)(dst + ebase + (size_t)(c0 + cc) * R + r0 + r8) = o;
  }
}

// ---------- fused MoE FFN v7: 512-thr blocks, 4 waves/SIMD ------------
// block = 8 waves x 16 tokens = 128 expert-slot rows, full D=256.
// Each wave owns 16 tokens end-to-end: acc f32x4[16] (64 AGPR) + xf 32
// VGPR -> ~120 regs/wave -> 4 waves/SIMD (2x v6's occupancy). Counted
// vmcnt 2-phase schedule retained (steady vmcnt(4), never 0 in loop).
// Stage B: the 32-f chunk is exactly one MFMA K -> P costs 1 ds_read.
// T1: e = bid&7 keeps each expert's weight reads inside its home XCD L2.
__global__ __launch_bounds__(512, 4) void ffn_kernel(
    const ushort_t* __restrict__ xbf, const ushort_t* __restrict__ w1t,
    const ushort_t* __restrict__ w2t, const float* __restrict__ B1,
    const float* __restrict__ B2, const int* __restrict__ tfs,
    const int* __restrict__ counts, const float* __restrict__ prob,
    float* __restrict__ Y)
{
  __shared__ __align__(16) ushort_t W1c[2][32 * 256];  // 2 x 16 KB
  __shared__ __align__(16) ushort_t W2c[2][256 * 32];  // 2 x 16 KB
  __shared__ __align__(16) ushort_t Pt[8][16 * 32];    // 8 x 1 KB, wave-private
  __shared__ __align__(16) float B1c[FF];              // 4 KB
  const int bid = blockIdx.x;
  const int e = bid & 7;                 // XCD-affinity: expert e -> XCD e
  const int row0 = (bid >> 3) * 128;
  if (row0 >= counts[e]) return;
  const int tid = threadIdx.x, lane = tid & 63, w = tid >> 6;
  const int q = lane >> 4, c = lane & 15;
  const int sbase = e * CAP + row0;
  const ushort_t* w1e = w1t + (size_t)e * FF * DD;
  const ushort_t* w2e = w2t + (size_t)e * DD * FF;

  const int t0 = tfs[sbase + w * 16 + c];
  const ushort_t* xr0 = xbf + (size_t)(t0 >= 0 ? t0 : 0) * DD;

  // persistent X fragments (B-operand rows): 32 VGPR
  bf16x8 xf0[8];
  #pragma unroll
  for (int ks = 0; ks < 8; ks++)
    xf0[ks] = *(const bf16x8*)(xr0 + ks * 32 + q * 8);

  const f32x4 fz = {0.f, 0.f, 0.f, 0.f};
  f32x4 acc[16];   // [dt over 256 d] x own 16 tokens: 64 AGPR
  #pragma unroll
  for (int dt = 0; dt < 16; dt++) acc[dt] = fz;

  auto issueW1 = [&](int chv, int bf) {
    const ushort_t* w1s = w1e + (size_t)(chv * 32) * DD;
    #pragma unroll
    for (int i = 0; i < 2; i++) {
      int id = i * 512 + tid, r = id >> 5, cc = id & 31;
      gll16(w1s + r * DD + ((cc ^ (r & 7)) * 8), &W1c[bf][id * 8]);
    }
  };
  auto issueW2 = [&](int chv, int bf) {
    const ushort_t* w2s = w2e + chv * 32;
    #pragma unroll
    for (int i = 0; i < 2; i++) {
      int id = i * 512 + tid, r = id >> 2, cc = id & 3;
      gll16(w2s + (size_t)r * FF + ((cc ^ (r & 3)) * 8), &W2c[bf][id * 8]);
    }
  };

  // prologue: first chunk's loads + B1 -> LDS, then one full drain.
  issueW1(0, 0);
  issueW2(0, 0);
  *(float2*)&B1c[tid * 2] = *(const float2*)(B1 + e * FF + tid * 2);
  __syncthreads();

  ushort_t* ptw = &Pt[w][0];
  const int prsl = ((2 * q) ^ (c & 6)) * 4;   // P read: 16B slot base (ush)

  for (int chv = 0; chv < 32; chv++) {
    const int bf = chv & 1;
    const int f0 = chv * 32;
    const bool last = (chv == 31);

    // ---- phase 1: W1(i+1) in flight; consume W1(i)
    if (!last) issueW1(chv + 1, bf ^ 1);
    if (!last) { asm volatile("s_waitcnt vmcnt(4)" ::: "memory"); }
    else       { asm volatile("s_waitcnt vmcnt(2)" ::: "memory"); }
    __builtin_amdgcn_s_barrier();

    // ---- stage A: P = relu(x @ w1 + b1), own 16 tokens, 32 f
    __builtin_amdgcn_s_setprio(1);
    #pragma unroll
    for (int ft = 0; ft < 2; ft++) {
      f32x4 pa = fz;
      const int fr = ft * 16 + c;
      #pragma unroll
      for (int ks = 0; ks < 8; ks++) {
        bf16x8 af = *(const bf16x8*)&W1c[bf][fr * 256 + (((ks * 4 + q) ^ (fr & 7)) * 8)];
        pa = __builtin_amdgcn_mfma_f32_16x16x32_bf16(af, xf0[ks], pa, 0, 0, 0);
      }
      float4 b1v = *(const float4*)&B1c[f0 + ft * 16 + q * 4];
      const float* bp = (const float*)&b1v;
      // lane (q,c) holds P[f=ft*16+q*4+r][tok c]; 8B slot (ft*4+q)^(c&6)
      // (even XOR key keeps the 16B read contiguous AND in f-order)
      ushort_t pkk[4];
      #pragma unroll
      for (int r = 0; r < 4; r++) {
        float v = pa[r] + bp[r];
        pkk[r] = f2bf(v > 0.f ? v : 0.f);
      }
      *(uint2*)&ptw[c * 32 + (((ft * 4 + q) ^ (c & 6)) * 4)] = *(const uint2*)pkk;
    }
    __builtin_amdgcn_s_setprio(0);

    // ---- phase 2: W2(i+1) in flight; consume W2(i)
    if (!last) issueW2(chv + 1, bf ^ 1);
    if (!last) { asm volatile("s_waitcnt vmcnt(4)" ::: "memory"); }
    else       { asm volatile("s_waitcnt vmcnt(0)" ::: "memory"); }
    __builtin_amdgcn_s_barrier();

    // ---- stage B: acc += P @ w2 (one K=32 MFMA per dt; P = 1 ds_read)
    __builtin_amdgcn_s_setprio(1);
    bf16x8 pf = *(const bf16x8*)&ptw[c * 32 + prsl];
    #pragma unroll
    for (int dt = 0; dt < 16; dt++) {
      bf16x8 wf = *(const bf16x8*)&W2c[bf][(dt * 16 + c) * 32 + ((q ^ (c & 3)) * 8)];
      acc[dt] = __builtin_amdgcn_mfma_f32_16x16x32_bf16(wf, pf, acc[dt], 0, 0, 0);
    }
    __builtin_amdgcn_s_setprio(0);
  }

  // ---- epilogue: (acc + b2) * prob -> Y (col=own token, row=d)
  const float p0 = (t0 >= 0) ? prob[t0] : 0.f;
  if (t0 >= 0) {
    #pragma unroll
    for (int dt = 0; dt < 16; dt++) {
      const int d0 = dt * 16 + q * 4;
      float4 b2v = *(const float4*)(B2 + e * DD + d0);
      float4 o;
      o.x = (acc[dt][0] + b2v.x) * p0;
      o.y = (acc[dt][1] + b2v.y) * p0;
      o.z = (acc[dt][2] + b2v.z) * p0;
      o.w = (acc[dt][3] + b2v.w) * p0;
      *(float4*)(Y + (size_t)t0 * DD + d0) = o;
    }
  }
}

extern "C" void kernel_launch(void* const* d_in, const int* in_sizes, int n_in,
                              void* d_out, int out_size, void* d_ws, size_t ws_size,
                              hipStream_t stream)
{
  const float* X  = (const float*)d_in[0];
  const float* GW = (const float*)d_in[1];
  const float* GB = (const float*)d_in[2];
  const float* W1 = (const float*)d_in[3];
  const float* B1 = (const float*)d_in[4];
  const float* W2 = (const float*)d_in[5];
  const float* B2 = (const float*)d_in[6];
  float* Y = (float*)d_out;

  char* p = (char*)d_ws;
  auto alloc = [&](size_t b) { char* r = p; p += (b + 255) & ~(size_t)255; return r; };
  ushort_t* xbf  = (ushort_t*)alloc((size_t)TT * DD * 2);        // x as bf16
  ushort_t* w1t  = (ushort_t*)alloc((size_t)EE * DD * FF * 2);   // [E][F][D] bf16
  ushort_t* w2t  = (ushort_t*)alloc((size_t)EE * FF * DD * 2);   // [E][D][F] bf16
  int*      eidx = (int*)alloc((size_t)TT * 4);
  float*    prob = (float*)alloc((size_t)TT * 4);
  int*      bh   = (int*)alloc(256 * EE * 4);
  int*      counts = (int*)alloc(EE * 4);
  int*      tfs  = (int*)alloc((size_t)EE * CAP * 4);
  // tfs needs no init: ws poison 0xAAAAAAAA is negative == "empty slot".

  hipMemsetAsync(bh, 0, 256 * EE * 4, stream);
  gate_cast_kernel<<<TT / 4, 256, 0, stream>>>(X, GW, GB, eidx, prob, xbf, bh);
  rankscan_kernel<<<256, 256, 0, stream>>>(eidx, bh, tfs, counts, Y);
  transpose2_kernel<<<1024, 256, 0, stream>>>(W1, W2, w1t, w2t);
  ffn_kernel<<<EE * 80, 512, 0, stream>>>(xbf, w1t, w2t, B1, B2, tfs, counts,
                                          prob, Y);
}

// Round 5
// 317.125 us; speedup vs baseline: 1.2490x; 1.2490x over previous
//
#include <hip/hip_runtime.h>
#include <stdint.h>

typedef unsigned short ushort_t;
typedef __bf16 bf16x8 __attribute__((ext_vector_type(8)));
typedef float f32x4 __attribute__((ext_vector_type(4)));

#define TT   65536   // tokens (8*8192)
#define DD   256
#define FF   1024
#define EE   8
#define CAP  10240   // ceil(1.25*T/E) == 80*128 exactly

typedef __attribute__((address_space(1))) void gvoid;
typedef __attribute__((address_space(3))) void lvoid;

__device__ inline unsigned short f2bf(float f) {
  unsigned int u = __builtin_bit_cast(unsigned int, f);
  u += 0x7fffu + ((u >> 16) & 1u);   // round-to-nearest-even
  return (unsigned short)(u >> 16);
}
__device__ inline void gll16(const void* g, void* l) {
  __builtin_amdgcn_global_load_lds((gvoid*)(uintptr_t)g, (lvoid*)(uintptr_t)l, 16, 0, 0);
}

// --- merged: gating+cast (blocks 0..2047, grid-stride, ZERO barriers)
//     and both weight transposes (blocks 2048..3071) in one dispatch ----
__global__ __launch_bounds__(256) void gatetrans_kernel(
    const float* __restrict__ X, const float* __restrict__ GW,
    const float* __restrict__ GB, int* __restrict__ eidx,
    float* __restrict__ prob, ushort_t* __restrict__ xbf,
    int* __restrict__ bh,
    const float* __restrict__ W1, const float* __restrict__ W2,
    ushort_t* __restrict__ w1t, ushort_t* __restrict__ w2t)
{
  if (blockIdx.x < 2048) {
    // ---------------- gating + f32->bf16 cast + histogram --------------
    // wave-private LDS slice; no __syncthreads anywhere (lgkmcnt only).
    __shared__ __align__(16) double gl[4][8][66];
    const int w = threadIdx.x >> 6, lane = threadIdx.x & 63;
    const int eg = lane >> 3, j = lane & 7;
    double gbv[EE];
    #pragma unroll
    for (int e = 0; e < EE; e++) gbv[e] = (double)GB[e];

    for (int tok = blockIdx.x * 4 + w; tok < TT; tok += 2048 * 4) {
      const float4 xv = *(const float4*)(X + (size_t)tok * DD + lane * 4);
      ushort_t pk[4] = {f2bf(xv.x), f2bf(xv.y), f2bf(xv.z), f2bf(xv.w)};
      *(uint2*)(xbf + (size_t)tok * DD + lane * 4) = *(const uint2*)pk;

      float xs[4] = {xv.x, xv.y, xv.z, xv.w};
      double acc[EE];
      #pragma unroll
      for (int e = 0; e < EE; e++) acc[e] = 0.0;
      #pragma unroll
      for (int dd = 0; dd < 4; dd++) {
        double xf = (double)xs[dd];
        const float4 g0 = *(const float4*)(GW + (size_t)(lane * 4 + dd) * EE);
        const float4 g1 = *(const float4*)(GW + (size_t)(lane * 4 + dd) * EE + 4);
        acc[0] += xf * (double)g0.x; acc[1] += xf * (double)g0.y;
        acc[2] += xf * (double)g0.z; acc[3] += xf * (double)g0.w;
        acc[4] += xf * (double)g1.x; acc[5] += xf * (double)g1.y;
        acc[6] += xf * (double)g1.z; acc[7] += xf * (double)g1.w;
      }
      // prior-iteration LDS reads retired before overwrite (same wave)
      asm volatile("s_waitcnt lgkmcnt(0)" ::: "memory");
      #pragma unroll
      for (int e = 0; e < EE; e++) gl[w][e][lane] = acc[e];
      asm volatile("s_waitcnt lgkmcnt(0)" ::: "memory");
      const double* rowp = gl[w][eg];
      double s = 0.0;
      #pragma unroll
      for (int k = 0; k < 8; k++) s += rowp[j * 8 + k];
      s += __shfl_xor(s, 4); s += __shfl_xor(s, 2); s += __shfl_xor(s, 1);
      // lane eg*8 now holds expert eg's logit; gather to all lanes
      double l8[EE];
      #pragma unroll
      for (int e = 0; e < EE; e++) l8[e] = __shfl(s, e * 8) + gbv[e];
      int best = 0; double bm = l8[0];
      #pragma unroll
      for (int e = 1; e < EE; e++) if (l8[e] > bm) { bm = l8[e]; best = e; }
      float sm = 0.f;
      #pragma unroll
      for (int e = 0; e < EE; e++) sm += __expf((float)(l8[e] - bm));
      if (lane == 0) {
        eidx[tok] = best; prob[tok] = 1.0f / sm;
        atomicAdd(&bh[(tok >> 8) * EE + best], 1);
      }
    }
  } else {
    // ---------------- weight transposes (f32->bf16) --------------------
    // XCD-affinity: expert e's tiles on XCD e (write-side L2 warmup).
    __shared__ __align__(16) ushort_t tile[64][72];
    int id = blockIdx.x - 2048;
    const float* src; ushort_t* dst; int R, Cc, bx, by, e;
    if (id < 512) {            // W1 [E][D][F] -> w1t [E][F][D]
      id = (id & 7) * 64 + (id >> 3);          // 512 = 8*64, bijective
      e = id >> 6; int r = id & 63; bx = r & 15; by = r >> 4;
      src = W1; dst = w1t; R = DD; Cc = FF;
    } else {                   // W2 [E][F][D] -> w2t [E][D][F]
      id -= 512;
      id = (id & 7) * 64 + (id >> 3);
      e = id >> 6; int r = id & 63; bx = r & 3; by = r >> 2;
      src = W2; dst = w2t; R = FF; Cc = DD;
    }
    const size_t ebase = (size_t)e * R * Cc;
    const int r0 = by * 64, c0 = bx * 64;
    #pragma unroll
    for (int it = 0; it < 4; it++) {
      int idx = threadIdx.x + it * 256;
      int r = idx >> 4, sl = idx & 15;
      float4 v = *(const float4*)(src + ebase + (size_t)(r0 + r) * Cc + c0 + sl * 4);
      ushort_t u[4] = {f2bf(v.x), f2bf(v.y), f2bf(v.z), f2bf(v.w)};
      *(uint2*)&tile[r][(sl ^ (r >> 3)) * 4] = *(const uint2*)u;
    }
    __syncthreads();
    #pragma unroll
    for (int it = 0; it < 2; it++) {
      int idx = threadIdx.x + it * 256;
      int cc = idx >> 3, r8 = (idx & 7) * 8;
      const int ccs = (((cc >> 2) ^ (r8 >> 3)) << 2) | (cc & 3);
      uint4 o;
      ushort_t* op = (ushort_t*)&o;
      #pragma unroll
      for (int jj = 0; jj < 8; jj++) op[jj] = tile[r8 + jj][ccs];
      *(uint4*)(dst + ebase + (size_t)(c0 + cc) * R + r0 + r8) = o;
    }
  }
}

// ------ merged scan+rank+zero-dropped: per block local reduction ------
__global__ __launch_bounds__(256) void rankscan_kernel(
    const int* __restrict__ eidx, const int* __restrict__ bh,
    int* __restrict__ tfs, int* __restrict__ counts, float* __restrict__ Y)
{
  __shared__ int tot[256][EE + 1];   // +1 pad: break 16-way bank conflict
  __shared__ int pre[256][EE + 1];
  __shared__ int wh[4][EE];
  __shared__ int base[EE];
  const int b = blockIdx.x, tid = threadIdx.x, w = tid >> 6, lane = tid & 63;
  #pragma unroll
  for (int e = 0; e < EE; e++) {
    int v = bh[tid * EE + e];
    tot[tid][e] = v;
    pre[tid][e] = (tid < b) ? v : 0;
  }
  __syncthreads();
  for (int off = 128; off >= 1; off >>= 1) {
    if (tid < off) {
      #pragma unroll
      for (int e = 0; e < EE; e++) {
        tot[tid][e] += tot[tid + off][e];
        pre[tid][e] += pre[tid + off][e];
      }
    }
    __syncthreads();
  }
  if (tid < EE) {
    if (b == 0) counts[tid] = tot[0][tid];
    base[tid] = pre[0][tid];
  }
  __syncthreads();
  const int t = b * 256 + tid;
  const int e = eidx[t];
  const unsigned long long ltmask = (1ull << lane) - 1ull;
  int myrank = 0;
  #pragma unroll
  for (int ee = 0; ee < EE; ee++) {
    unsigned long long m = __ballot(e == ee);
    if (e == ee) myrank = __popcll(m & ltmask);
    if (lane == 0) wh[w][ee] = __popcll(m);
  }
  __syncthreads();
  int pos = base[e] + myrank;
  for (int ww = 0; ww < w; ww++) pos += wh[ww][e];
  if (pos < CAP) {
    tfs[e * CAP + pos] = t;
  } else {
    float4 z = {0.f, 0.f, 0.f, 0.f};
    float4* yp = (float4*)(Y + (size_t)t * DD);
    for (int i = 0; i < DD / 4; i++) yp[i] = z;
  }
}

// --------- fused MoE FFN v8: counted-vmcnt + d-split stage B ----------
// v6's schedule (2-phase counted vmcnt, never 0 in loop; T1 e=bid&7
// affinity; B1 in LDS) + v3's stage-B work split (wave = 64 d x ALL 128
// tokens -> each wave reads only its W2 slice: 28 b128 reads/wave/chunk
// vs v6's 34, on a ~79% LDS-pipe-bound kernel).
// Pt is block-shared: lgkmcnt(0) added before the phase-2 barrier.
__global__ __launch_bounds__(256, 2) void ffn_kernel(
    const ushort_t* __restrict__ xbf, const ushort_t* __restrict__ w1t,
    const ushort_t* __restrict__ w2t, const float* __restrict__ B1,
    const float* __restrict__ B2, const int* __restrict__ tfs,
    const int* __restrict__ counts, const float* __restrict__ prob,
    float* __restrict__ Y)
{
  __shared__ __align__(16) ushort_t W1c[2][32 * 256];  // 2 x 16 KB
  __shared__ __align__(16) ushort_t W2c[2][256 * 32];  // 2 x 16 KB
  __shared__ __align__(16) ushort_t Pt[128 * 32];      // 8 KB, block-shared
  __shared__ __align__(16) float B1c[FF];              // 4 KB
  const int bid = blockIdx.x;
  const int e = bid & 7;                 // XCD-affinity: expert e -> XCD e
  const int row0 = (bid >> 3) * 128;
  if (row0 >= counts[e]) return;
  const int tid = threadIdx.x, lane = tid & 63, w = tid >> 6;
  const int q = lane >> 4, c = lane & 15;
  const int sbase = e * CAP + row0;
  const ushort_t* w1e = w1t + (size_t)e * FF * DD;
  const ushort_t* w2e = w2t + (size_t)e * DD * FF;

  const int t0 = tfs[sbase + w * 32 + c];
  const int t1 = tfs[sbase + w * 32 + 16 + c];
  const ushort_t* xr0 = xbf + (size_t)(t0 >= 0 ? t0 : 0) * DD;
  const ushort_t* xr1 = xbf + (size_t)(t1 >= 0 ? t1 : 0) * DD;

  // persistent X fragments (B-operand rows): 64 VGPR
  bf16x8 xf0[8], xf1[8];
  #pragma unroll
  for (int ks = 0; ks < 8; ks++) {
    xf0[ks] = *(const bf16x8*)(xr0 + ks * 32 + q * 8);
    xf1[ks] = *(const bf16x8*)(xr1 + ks * 32 + q * 8);
  }

  const f32x4 fz = {0.f, 0.f, 0.f, 0.f};
  f32x4 acc[4][8];   // [dt over 64 d][tn over 128 tokens]
  #pragma unroll
  for (int dt = 0; dt < 4; dt++)
    #pragma unroll
    for (int tn = 0; tn < 8; tn++) acc[dt][tn] = fz;

  auto issueW1 = [&](int chv, int bf) {
    const ushort_t* w1s = w1e + (size_t)(chv * 32) * DD;
    #pragma unroll
    for (int i = 0; i < 4; i++) {
      int id = i * 256 + tid, r = id >> 5, cc = id & 31;
      gll16(w1s + r * DD + ((cc ^ (r & 7)) * 8), &W1c[bf][id * 8]);
    }
  };
  auto issueW2 = [&](int chv, int bf) {
    const ushort_t* w2s = w2e + chv * 32;
    #pragma unroll
    for (int i = 0; i < 4; i++) {
      int id = i * 256 + tid, r = id >> 2, cc = id & 3;
      gll16(w2s + (size_t)r * FF + ((cc ^ (r & 3)) * 8), &W2c[bf][id * 8]);
    }
  };

  // prologue: first chunk's loads + B1 -> LDS, then one full drain.
  issueW1(0, 0);
  issueW2(0, 0);
  *(float4*)&B1c[tid * 4] = *(const float4*)(B1 + e * FF + tid * 4);
  __syncthreads();

  for (int chv = 0; chv < 32; chv++) {
    const int bf = chv & 1;
    const int f0 = chv * 32;
    const bool last = (chv == 31);

    // ---- phase 1: W1(i+1) in flight; consume W1(i)
    if (!last) issueW1(chv + 1, bf ^ 1);
    if (!last) { asm volatile("s_waitcnt vmcnt(8)" ::: "memory"); }
    else       { asm volatile("s_waitcnt vmcnt(4)" ::: "memory"); }
    __builtin_amdgcn_s_barrier();

    // ---- stage A: P = relu(x @ w1 + b1), own 32 tokens, 32 f
    __builtin_amdgcn_s_setprio(1);
    #pragma unroll
    for (int ft = 0; ft < 2; ft++) {
      f32x4 pa0 = fz, pa1 = fz;
      const int fr = ft * 16 + c;
      #pragma unroll
      for (int ks = 0; ks < 8; ks++) {
        bf16x8 af = *(const bf16x8*)&W1c[bf][fr * 256 + (((ks * 4 + q) ^ (fr & 7)) * 8)];
        pa0 = __builtin_amdgcn_mfma_f32_16x16x32_bf16(af, xf0[ks], pa0, 0, 0, 0);
        pa1 = __builtin_amdgcn_mfma_f32_16x16x32_bf16(af, xf1[ks], pa1, 0, 0, 0);
      }
      float4 b1v = *(const float4*)&B1c[f0 + ft * 16 + q * 4];
      const float* bp = (const float*)&b1v;
      const int ch16 = (ft * 2 + (q >> 1));
      #pragma unroll
      for (int tn2 = 0; tn2 < 2; tn2++) {
        const f32x4& pa = tn2 ? pa1 : pa0;
        ushort_t pkk[4];
        #pragma unroll
        for (int r = 0; r < 4; r++) {
          float v = pa[r] + bp[r];
          pkk[r] = f2bf(v > 0.f ? v : 0.f);
        }
        int tokl = w * 32 + tn2 * 16 + c;
        *(uint2*)&Pt[tokl * 32 + ((ch16 ^ (c & 3)) * 8) + (q & 1) * 4] = *(const uint2*)pkk;
      }
    }
    __builtin_amdgcn_s_setprio(0);

    // ---- phase 2: W2(i+1) in flight; consume W2(i)
    if (!last) issueW2(chv + 1, bf ^ 1);
    // flush this wave's Pt writes (raw s_barrier has no implicit drain),
    // then wait the counted DMA quota.
    if (!last) { asm volatile("s_waitcnt vmcnt(8) lgkmcnt(0)" ::: "memory"); }
    else       { asm volatile("s_waitcnt vmcnt(0) lgkmcnt(0)" ::: "memory"); }
    __builtin_amdgcn_s_barrier();

    // ---- stage B: acc += P @ w2 (this wave: 64 d x ALL 128 tokens)
    __builtin_amdgcn_s_setprio(1);
    bf16x8 wf[4];
    #pragma unroll
    for (int dt = 0; dt < 4; dt++) {
      const int dr = w * 64 + dt * 16 + c;
      wf[dt] = *(const bf16x8*)&W2c[bf][dr * 32 + ((q ^ (c & 3)) * 8)];
    }
    #pragma unroll
    for (int hh = 0; hh < 2; hh++) {
      bf16x8 pf[4];
      #pragma unroll
      for (int t4 = 0; t4 < 4; t4++)
        pf[t4] = *(const bf16x8*)&Pt[((hh * 4 + t4) * 16 + c) * 32 + ((q ^ (c & 3)) * 8)];
      #pragma unroll
      for (int dt = 0; dt < 4; dt++) {
        #pragma unroll
        for (int t4 = 0; t4 < 4; t4++)
          acc[dt][hh * 4 + t4] =
              __builtin_amdgcn_mfma_f32_16x16x32_bf16(wf[dt], pf[t4], acc[dt][hh * 4 + t4], 0, 0, 0);
      }
    }
    __builtin_amdgcn_s_setprio(0);
  }

  // ---- epilogue: (acc + b2) * prob -> Y (col=token, row=d-local)
  int tE[8]; float pE[8];
  #pragma unroll
  for (int tn = 0; tn < 8; tn++) {
    tE[tn] = tfs[sbase + tn * 16 + c];
    pE[tn] = (tE[tn] >= 0) ? prob[tE[tn]] : 0.f;
  }
  #pragma unroll
  for (int dt = 0; dt < 4; dt++) {
    const int d0 = w * 64 + dt * 16 + q * 4;
    float4 b2v = *(const float4*)(B2 + e * DD + d0);
    #pragma unroll
    for (int tn = 0; tn < 8; tn++) {
      if (tE[tn] >= 0) {
        float4 o;
        o.x = (acc[dt][tn][0] + b2v.x) * pE[tn];
        o.y = (acc[dt][tn][1] + b2v.y) * pE[tn];
        o.z = (acc[dt][tn][2] + b2v.z) * pE[tn];
        o.w = (acc[dt][tn][3] + b2v.w) * pE[tn];
        *(float4*)(Y + (size_t)tE[tn] * DD + d0) = o;
      }
    }
  }
}

extern "C" void kernel_launch(void* const* d_in, const int* in_sizes, int n_in,
                              void* d_out, int out_size, void* d_ws, size_t ws_size,
                              hipStream_t stream)
{
  const float* X  = (const float*)d_in[0];
  const float* GW = (const float*)d_in[1];
  const float* GB = (const float*)d_in[2];
  const float* W1 = (const float*)d_in[3];
  const float* B1 = (const float*)d_in[4];
  const float* W2 = (const float*)d_in[5];
  const float* B2 = (const float*)d_in[6];
  float* Y = (float*)d_out;

  char* p = (char*)d_ws;
  auto alloc = [&](size_t b) { char* r = p; p += (b + 255) & ~(size_t)255; return r; };
  ushort_t* xbf  = (ushort_t*)alloc((size_t)TT * DD * 2);        // x as bf16
  ushort_t* w1t  = (ushort_t*)alloc((size_t)EE * DD * FF * 2);   // [E][F][D] bf16
  ushort_t* w2t  = (ushort_t*)alloc((size_t)EE * FF * DD * 2);   // [E][D][F] bf16
  int*      eidx = (int*)alloc((size_t)TT * 4);
  float*    prob = (float*)alloc((size_t)TT * 4);
  int*      bh   = (int*)alloc(256 * EE * 4);
  int*      counts = (int*)alloc(EE * 4);
  int*      tfs  = (int*)alloc((size_t)EE * CAP * 4);
  // tfs needs no init: ws poison 0xAAAAAAAA is negative == "empty slot".

  hipMemsetAsync(bh, 0, 256 * EE * 4, stream);
  gatetrans_kernel<<<3072, 256, 0, stream>>>(X, GW, GB, eidx, prob, xbf, bh,
                                             W1, W2, w1t, w2t);
  rankscan_kernel<<<256, 256, 0, stream>>>(eidx, bh, tfs, counts, Y);
  ffn_kernel<<<EE * 80, 256, 0, stream>>>(xbf, w1t, w2t, B1, B2, tfs, counts,
                                          prob, Y);
}

// Round 6
// 291.753 us; speedup vs baseline: 1.3576x; 1.0870x over previous
//
#include <hip/hip_runtime.h>
#include <stdint.h>

typedef unsigned short ushort_t;
typedef __bf16 bf16x8 __attribute__((ext_vector_type(8)));
typedef float f32x4 __attribute__((ext_vector_type(4)));

#define TT   65536   // tokens (8*8192)
#define DD   256
#define FF   1024
#define EE   8
#define CAP  10240   // ceil(1.25*T/E) == 80*128 exactly

typedef __attribute__((address_space(1))) void gvoid;
typedef __attribute__((address_space(3))) void lvoid;

__device__ inline unsigned short f2bf(float f) {
  unsigned int u = __builtin_bit_cast(unsigned int, f);
  u += 0x7fffu + ((u >> 16) & 1u);   // round-to-nearest-even
  return (unsigned short)(u >> 16);
}
__device__ inline void gll16(const void* g, void* l) {
  __builtin_amdgcn_global_load_lds((gvoid*)(uintptr_t)g, (lvoid*)(uintptr_t)l, 16, 0, 0);
}
// 4-slot key spreading rows 0..15 over 4 slots with 2-per-slot per parity
// class: kills the 4-way wf conflict (lanes c,c+4,c+8,c+12 same bank-quad).
__device__ inline int sw4(int r) { return (r ^ (r >> 2)) & 3; }

// --- merged: gating+cast (blocks 0..2047, grid-stride, ZERO barriers)
//     and both weight transposes (blocks 2048..3071) in one dispatch ----
__global__ __launch_bounds__(256) void gatetrans_kernel(
    const float* __restrict__ X, const float* __restrict__ GW,
    const float* __restrict__ GB, int* __restrict__ eidx,
    float* __restrict__ prob, ushort_t* __restrict__ xbf,
    int* __restrict__ bh,
    const float* __restrict__ W1, const float* __restrict__ W2,
    ushort_t* __restrict__ w1t, ushort_t* __restrict__ w2t)
{
  if (blockIdx.x < 2048) {
    // ---------------- gating + f32->bf16 cast + histogram --------------
    // wave-private LDS slice; no __syncthreads anywhere (lgkmcnt only).
    __shared__ __align__(16) double gl[4][8][66];
    const int w = threadIdx.x >> 6, lane = threadIdx.x & 63;
    const int eg = lane >> 3, j = lane & 7;
    double gbv[EE];
    #pragma unroll
    for (int e = 0; e < EE; e++) gbv[e] = (double)GB[e];

    for (int tok = blockIdx.x * 4 + w; tok < TT; tok += 2048 * 4) {
      const float4 xv = *(const float4*)(X + (size_t)tok * DD + lane * 4);
      ushort_t pk[4] = {f2bf(xv.x), f2bf(xv.y), f2bf(xv.z), f2bf(xv.w)};
      *(uint2*)(xbf + (size_t)tok * DD + lane * 4) = *(const uint2*)pk;

      float xs[4] = {xv.x, xv.y, xv.z, xv.w};
      double acc[EE];
      #pragma unroll
      for (int e = 0; e < EE; e++) acc[e] = 0.0;
      #pragma unroll
      for (int dd = 0; dd < 4; dd++) {
        double xf = (double)xs[dd];
        const float4 g0 = *(const float4*)(GW + (size_t)(lane * 4 + dd) * EE);
        const float4 g1 = *(const float4*)(GW + (size_t)(lane * 4 + dd) * EE + 4);
        acc[0] += xf * (double)g0.x; acc[1] += xf * (double)g0.y;
        acc[2] += xf * (double)g0.z; acc[3] += xf * (double)g0.w;
        acc[4] += xf * (double)g1.x; acc[5] += xf * (double)g1.y;
        acc[6] += xf * (double)g1.z; acc[7] += xf * (double)g1.w;
      }
      // prior-iteration LDS reads retired before overwrite (same wave)
      asm volatile("s_waitcnt lgkmcnt(0)" ::: "memory");
      #pragma unroll
      for (int e = 0; e < EE; e++) gl[w][e][lane] = acc[e];
      asm volatile("s_waitcnt lgkmcnt(0)" ::: "memory");
      const double* rowp = gl[w][eg];
      double s = 0.0;
      #pragma unroll
      for (int k = 0; k < 8; k++) s += rowp[j * 8 + k];
      s += __shfl_xor(s, 4); s += __shfl_xor(s, 2); s += __shfl_xor(s, 1);
      // lane eg*8 now holds expert eg's logit; gather to all lanes
      double l8[EE];
      #pragma unroll
      for (int e = 0; e < EE; e++) l8[e] = __shfl(s, e * 8) + gbv[e];
      int best = 0; double bm = l8[0];
      #pragma unroll
      for (int e = 1; e < EE; e++) if (l8[e] > bm) { bm = l8[e]; best = e; }
      float sm = 0.f;
      #pragma unroll
      for (int e = 0; e < EE; e++) sm += __expf((float)(l8[e] - bm));
      if (lane == 0) {
        eidx[tok] = best; prob[tok] = 1.0f / sm;
        atomicAdd(&bh[(tok >> 8) * EE + best], 1);
      }
    }
  } else {
    // ---------------- weight transposes (f32->bf16) --------------------
    // XCD-affinity: expert e's tiles on XCD e (write-side L2 warmup).
    __shared__ __align__(16) ushort_t tile[64][72];
    int id = blockIdx.x - 2048;
    const float* src; ushort_t* dst; int R, Cc, bx, by, e;
    if (id < 512) {            // W1 [E][D][F] -> w1t [E][F][D]
      id = (id & 7) * 64 + (id >> 3);          // 512 = 8*64, bijective
      e = id >> 6; int r = id & 63; bx = r & 15; by = r >> 4;
      src = W1; dst = w1t; R = DD; Cc = FF;
    } else {                   // W2 [E][F][D] -> w2t [E][D][F]
      id -= 512;
      id = (id & 7) * 64 + (id >> 3);
      e = id >> 6; int r = id & 63; bx = r & 3; by = r >> 2;
      src = W2; dst = w2t; R = FF; Cc = DD;
    }
    const size_t ebase = (size_t)e * R * Cc;
    const int r0 = by * 64, c0 = bx * 64;
    #pragma unroll
    for (int it = 0; it < 4; it++) {
      int idx = threadIdx.x + it * 256;
      int r = idx >> 4, sl = idx & 15;
      float4 v = *(const float4*)(src + ebase + (size_t)(r0 + r) * Cc + c0 + sl * 4);
      ushort_t u[4] = {f2bf(v.x), f2bf(v.y), f2bf(v.z), f2bf(v.w)};
      *(uint2*)&tile[r][(sl ^ (r >> 3)) * 4] = *(const uint2*)u;
    }
    __syncthreads();
    #pragma unroll
    for (int it = 0; it < 2; it++) {
      int idx = threadIdx.x + it * 256;
      int cc = idx >> 3, r8 = (idx & 7) * 8;
      const int ccs = (((cc >> 2) ^ (r8 >> 3)) << 2) | (cc & 3);
      uint4 o;
      ushort_t* op = (ushort_t*)&o;
      #pragma unroll
      for (int jj = 0; jj < 8; jj++) op[jj] = tile[r8 + jj][ccs];
      *(uint4*)(dst + ebase + (size_t)(c0 + cc) * R + r0 + r8) = o;
    }
  }
}

// ------ merged scan+rank+zero-dropped: per block local reduction ------
__global__ __launch_bounds__(256) void rankscan_kernel(
    const int* __restrict__ eidx, const int* __restrict__ bh,
    int* __restrict__ tfs, int* __restrict__ counts, float* __restrict__ Y)
{
  __shared__ int tot[256][EE + 1];   // +1 pad: break 16-way bank conflict
  __shared__ int pre[256][EE + 1];
  __shared__ int wh[4][EE];
  __shared__ int base[EE];
  const int b = blockIdx.x, tid = threadIdx.x, w = tid >> 6, lane = tid & 63;
  #pragma unroll
  for (int e = 0; e < EE; e++) {
    int v = bh[tid * EE + e];
    tot[tid][e] = v;
    pre[tid][e] = (tid < b) ? v : 0;
  }
  __syncthreads();
  for (int off = 128; off >= 1; off >>= 1) {
    if (tid < off) {
      #pragma unroll
      for (int e = 0; e < EE; e++) {
        tot[tid][e] += tot[tid + off][e];
        pre[tid][e] += pre[tid + off][e];
      }
    }
    __syncthreads();
  }
  if (tid < EE) {
    if (b == 0) counts[tid] = tot[0][tid];
    base[tid] = pre[0][tid];
  }
  __syncthreads();
  const int t = b * 256 + tid;
  const int e = eidx[t];
  const unsigned long long ltmask = (1ull << lane) - 1ull;
  int myrank = 0;
  #pragma unroll
  for (int ee = 0; ee < EE; ee++) {
    unsigned long long m = __ballot(e == ee);
    if (e == ee) myrank = __popcll(m & ltmask);
    if (lane == 0) wh[w][ee] = __popcll(m);
  }
  __syncthreads();
  int pos = base[e] + myrank;
  for (int ww = 0; ww < w; ww++) pos += wh[ww][e];
  if (pos < CAP) {
    tfs[e * CAP + pos] = t;
  } else {
    float4 z = {0.f, 0.f, 0.f, 0.f};
    float4* yp = (float4*)(Y + (size_t)t * DD);
    for (int i = 0; i < DD / 4; i++) yp[i] = z;
  }
}

// ---- fused MoE FFN v9: v6 structure + sw4 key on W2c (single change) --
// v6 (measured 141 us): 2-phase counted vmcnt (never 0 in loop), raw
// s_barrier, T1 e=bid&7 XCD affinity, setprio, B1 in LDS, wave-private
// Pt, token-private stage B (16 independent acc chains).
// v9 delta: W2c slot key (r&3)->sw4(r) on staging and (c&3)->sw4(c) on
// the wf read -- fixes the one remaining 4-way LDS bank conflict
// (lanes c,c+4,c+8,c+12 shared a bank-quad under the old key).
__global__ __launch_bounds__(256, 2) void ffn_kernel(
    const ushort_t* __restrict__ xbf, const ushort_t* __restrict__ w1t,
    const ushort_t* __restrict__ w2t, const float* __restrict__ B1,
    const float* __restrict__ B2, const int* __restrict__ tfs,
    const int* __restrict__ counts, const float* __restrict__ prob,
    float* __restrict__ Y)
{
  __shared__ __align__(16) ushort_t W1c[2][32 * 256];  // 2 x 16 KB
  __shared__ __align__(16) ushort_t W2c[2][256 * 32];  // 2 x 16 KB
  __shared__ __align__(16) ushort_t Pt[4][32 * 32];    // 4 x 2 KB, wave-private
  __shared__ __align__(16) float B1c[FF];              // 4 KB
  const int bid = blockIdx.x;
  const int e = bid & 7;                 // XCD-affinity: expert e -> XCD e
  const int row0 = (bid >> 3) * 128;
  if (row0 >= counts[e]) return;
  const int tid = threadIdx.x, lane = tid & 63, w = tid >> 6;
  const int q = lane >> 4, c = lane & 15;
  const int sbase = e * CAP + row0;
  const ushort_t* w1e = w1t + (size_t)e * FF * DD;
  const ushort_t* w2e = w2t + (size_t)e * DD * FF;

  const int t0 = tfs[sbase + w * 32 + c];
  const int t1 = tfs[sbase + w * 32 + 16 + c];
  const ushort_t* xr0 = xbf + (size_t)(t0 >= 0 ? t0 : 0) * DD;
  const ushort_t* xr1 = xbf + (size_t)(t1 >= 0 ? t1 : 0) * DD;

  // persistent X fragments (B-operand rows): 64 VGPR
  bf16x8 xf0[8], xf1[8];
  #pragma unroll
  for (int ks = 0; ks < 8; ks++) {
    xf0[ks] = *(const bf16x8*)(xr0 + ks * 32 + q * 8);
    xf1[ks] = *(const bf16x8*)(xr1 + ks * 32 + q * 8);
  }

  const f32x4 fz = {0.f, 0.f, 0.f, 0.f};
  f32x4 acc[16][2];   // [dt over 256 d][tn over own 32 tokens]
  #pragma unroll
  for (int dt = 0; dt < 16; dt++) {
    acc[dt][0] = fz; acc[dt][1] = fz;
  }

  auto issueW1 = [&](int chv, int bf) {
    const ushort_t* w1s = w1e + (size_t)(chv * 32) * DD;
    #pragma unroll
    for (int i = 0; i < 4; i++) {
      int id = i * 256 + tid, r = id >> 5, cc = id & 31;
      gll16(w1s + r * DD + ((cc ^ (r & 7)) * 8), &W1c[bf][id * 8]);
    }
  };
  auto issueW2 = [&](int chv, int bf) {
    const ushort_t* w2s = w2e + chv * 32;
    #pragma unroll
    for (int i = 0; i < 4; i++) {
      int id = i * 256 + tid, r = id >> 2, cc = id & 3;
      gll16(w2s + (size_t)r * FF + ((cc ^ sw4(r)) * 8), &W2c[bf][id * 8]);
    }
  };

  // prologue: first chunk's loads + B1 -> LDS, then one full drain.
  issueW1(0, 0);
  issueW2(0, 0);
  *(float4*)&B1c[tid * 4] = *(const float4*)(B1 + e * FF + tid * 4);
  __syncthreads();

  ushort_t* ptw = &Pt[w][0];
  const int psl = ((2 * q) ^ (c & 6)) * 4;   // P read slot (8B units *4 ush)

  for (int chv = 0; chv < 32; chv++) {
    const int bf = chv & 1;
    const int f0 = chv * 32;
    const bool last = (chv == 31);

    // ---- phase 1: W1(i+1) in flight; consume W1(i)
    if (!last) issueW1(chv + 1, bf ^ 1);
    if (!last) { asm volatile("s_waitcnt vmcnt(8)" ::: "memory"); }
    else       { asm volatile("s_waitcnt vmcnt(4)" ::: "memory"); }
    __builtin_amdgcn_s_barrier();

    // ---- stage A: P = relu(x @ w1 + b1), own 32 tokens, 32 f
    __builtin_amdgcn_s_setprio(1);
    #pragma unroll
    for (int ft = 0; ft < 2; ft++) {
      f32x4 pa0 = fz, pa1 = fz;
      const int fr = ft * 16 + c;
      #pragma unroll
      for (int ks = 0; ks < 8; ks++) {
        bf16x8 af = *(const bf16x8*)&W1c[bf][fr * 256 + (((ks * 4 + q) ^ (fr & 7)) * 8)];
        pa0 = __builtin_amdgcn_mfma_f32_16x16x32_bf16(af, xf0[ks], pa0, 0, 0, 0);
        pa1 = __builtin_amdgcn_mfma_f32_16x16x32_bf16(af, xf1[ks], pa1, 0, 0, 0);
      }
      float4 b1v = *(const float4*)&B1c[f0 + ft * 16 + q * 4];
      const float* bp = (const float*)&b1v;
      // lane (q,c) holds P[f=ft*16+q*4+r][tok=tn2*16+c]; store 8B at
      // slot (ft*4+q) XOR (c&6)  (even key keeps 16B reads contiguous)
      const int sl = ((ft * 4 + q) ^ (c & 6)) * 4;
      #pragma unroll
      for (int tn2 = 0; tn2 < 2; tn2++) {
        const f32x4& pa = tn2 ? pa1 : pa0;
        ushort_t pkk[4];
        #pragma unroll
        for (int r = 0; r < 4; r++) {
          float v = pa[r] + bp[r];
          pkk[r] = f2bf(v > 0.f ? v : 0.f);
        }
        *(uint2*)&ptw[(tn2 * 16 + c) * 32 + sl] = *(const uint2*)pkk;
      }
    }
    __builtin_amdgcn_s_setprio(0);

    // ---- phase 2: W2(i+1) in flight; consume W2(i)
    if (!last) issueW2(chv + 1, bf ^ 1);
    if (!last) { asm volatile("s_waitcnt vmcnt(8)" ::: "memory"); }
    else       { asm volatile("s_waitcnt vmcnt(0)" ::: "memory"); }
    __builtin_amdgcn_s_barrier();

    // ---- stage B: acc += P @ w2 (wave-private P)
    __builtin_amdgcn_s_setprio(1);
    bf16x8 pf0 = *(const bf16x8*)&ptw[c * 32 + psl];
    bf16x8 pf1 = *(const bf16x8*)&ptw[(16 + c) * 32 + psl];
    #pragma unroll
    for (int dt = 0; dt < 16; dt++) {
      bf16x8 wf = *(const bf16x8*)&W2c[bf][(dt * 16 + c) * 32 + ((q ^ sw4(c)) * 8)];
      acc[dt][0] = __builtin_amdgcn_mfma_f32_16x16x32_bf16(wf, pf0, acc[dt][0], 0, 0, 0);
      acc[dt][1] = __builtin_amdgcn_mfma_f32_16x16x32_bf16(wf, pf1, acc[dt][1], 0, 0, 0);
    }
    __builtin_amdgcn_s_setprio(0);
  }

  // ---- epilogue: (acc + b2) * prob -> Y (col=own token, row=d)
  const float p0 = (t0 >= 0) ? prob[t0] : 0.f;
  const float p1 = (t1 >= 0) ? prob[t1] : 0.f;
  #pragma unroll
  for (int dt = 0; dt < 16; dt++) {
    const int d0 = dt * 16 + q * 4;
    float4 b2v = *(const float4*)(B2 + e * DD + d0);
    if (t0 >= 0) {
      float4 o;
      o.x = (acc[dt][0][0] + b2v.x) * p0;
      o.y = (acc[dt][0][1] + b2v.y) * p0;
      o.z = (acc[dt][0][2] + b2v.z) * p0;
      o.w = (acc[dt][0][3] + b2v.w) * p0;
      *(float4*)(Y + (size_t)t0 * DD + d0) = o;
    }
    if (t1 >= 0) {
      float4 o;
      o.x = (acc[dt][1][0] + b2v.x) * p1;
      o.y = (acc[dt][1][1] + b2v.y) * p1;
      o.z = (acc[dt][1][2] + b2v.z) * p1;
      o.w = (acc[dt][1][3] + b2v.w) * p1;
      *(float4*)(Y + (size_t)t1 * DD + d0) = o;
    }
  }
}

extern "C" void kernel_launch(void* const* d_in, const int* in_sizes, int n_in,
                              void* d_out, int out_size, void* d_ws, size_t ws_size,
                              hipStream_t stream)
{
  const float* X  = (const float*)d_in[0];
  const float* GW = (const float*)d_in[1];
  const float* GB = (const float*)d_in[2];
  const float* W1 = (const float*)d_in[3];
  const float* B1 = (const float*)d_in[4];
  const float* W2 = (const float*)d_in[5];
  const float* B2 = (const float*)d_in[6];
  float* Y = (float*)d_out;

  char* p = (char*)d_ws;
  auto alloc = [&](size_t b) { char* r = p; p += (b + 255) & ~(size_t)255; return r; };
  ushort_t* xbf  = (ushort_t*)alloc((size_t)TT * DD * 2);        // x as bf16
  ushort_t* w1t  = (ushort_t*)alloc((size_t)EE * DD * FF * 2);   // [E][F][D] bf16
  ushort_t* w2t  = (ushort_t*)alloc((size_t)EE * FF * DD * 2);   // [E][D][F] bf16
  int*      eidx = (int*)alloc((size_t)TT * 4);
  float*    prob = (float*)alloc((size_t)TT * 4);
  int*      bh   = (int*)alloc(256 * EE * 4);
  int*      counts = (int*)alloc(EE * 4);
  int*      tfs  = (int*)alloc((size_t)EE * CAP * 4);
  // tfs needs no init: ws poison 0xAAAAAAAA is negative == "empty slot".

  hipMemsetAsync(bh, 0, 256 * EE * 4, stream);
  gatetrans_kernel<<<3072, 256, 0, stream>>>(X, GW, GB, eidx, prob, xbf, bh,
                                             W1, W2, w1t, w2t);
  rankscan_kernel<<<256, 256, 0, stream>>>(eidx, bh, tfs, counts, Y);
  ffn_kernel<<<EE * 80, 256, 0, stream>>>(xbf, w1t, w2t, B1, B2, tfs, counts,
                                          prob, Y);
}